// Round 1
// baseline (971.395 us; speedup 1.0000x reference)
//
#include <hip/hip_runtime.h>

// GRUFeatureExtractor: 2-layer GRU (B=4096, T=256, D_IN=128, H=64) + FC -> [B,1]
// Single fused persistent kernel: streams x once (537 MB = the HBM floor),
// never materializes gx0 / h1_seq / h2_seq. 256 blocks (1/CU) x 4 waves.
// Block owns 16 batch rows; wave owns 16 h-cols (r/z/n N-tiles {16w,64+16w,128+16w}).
// f16 MFMA operands (2^-11 rel err -> recurrence err ~1e-4 << 6.9e-3 threshold),
// fp32 accumulation, fp32 biases as accumulator init.
// Weights: 30 B-fragments kept in VGPRs across the whole T-loop (launch_bounds(256,1)).
// h1/h2: double-buffered LDS (C-layout -> A-layout cross-wave transform),
// exactly ONE barrier per timestep. x: distance-2 register prefetch.
//
// R1 change: the per-step barrier is now lgkmcnt-only + raw s_barrier.
// __syncthreads() lowers to `s_waitcnt vmcnt(0) lgkmcnt(0); s_barrier`, which
// drained the 8 just-issued x-prefetch HBM loads EVERY timestep (~900 cyc
// exposed latency/step, m126), structurally killing the distance-2 pipeline.
// The barrier only orders the LDS h-exchange -> lgkmcnt(0) suffices; x loads
// are wave-private VGPR loads and may stay in flight across the barrier (T4).

#define TT  256
#define DIN 128
#define HH  64

typedef _Float16 f16x8 __attribute__((ext_vector_type(8)));
typedef float    f32x4 __attribute__((ext_vector_type(4)));

__device__ __forceinline__ float fast_sigmoid(float x) {
    float e = __builtin_amdgcn_exp2f(-1.44269504088896f * x);
    return __builtin_amdgcn_rcpf(1.0f + e);
}
__device__ __forceinline__ float fast_tanh(float x) {
    // tanh(x) = 1 - 2/(exp2(2*log2e*x)+1); saturates correctly at +-inf
    float e = __builtin_amdgcn_exp2f(2.88539008177793f * x);
    return 1.0f - 2.0f * __builtin_amdgcn_rcpf(1.0f + e);
}

// LDS-only barrier: waits for this wave's outstanding DS ops (producer-side
// write visibility), then raw s_barrier. Does NOT drain vmcnt -> global
// prefetch loads stay in flight across timesteps. Memory-clobber asm on both
// sides pins all DS ops to their side of the barrier (rule #18 discipline).
__device__ __forceinline__ void lds_barrier() {
    asm volatile("s_waitcnt lgkmcnt(0)" ::: "memory");
    __builtin_amdgcn_s_barrier();
    asm volatile("" ::: "memory");
}

__global__ __launch_bounds__(256, 1) void gru_fused_kernel(
    const float* __restrict__ x,
    const float* __restrict__ Wih0, const float* __restrict__ Whh0,
    const float* __restrict__ bih0, const float* __restrict__ bhh0,
    const float* __restrict__ Wih1, const float* __restrict__ Whh1,
    const float* __restrict__ bih1, const float* __restrict__ bhh1,
    const float* __restrict__ Wfc,  const float* __restrict__ bfc,
    float* __restrict__ out)
{
    const int tid  = threadIdx.x;
    const int wv   = tid >> 6;      // wave 0..3
    const int lane = tid & 63;
    const int q    = lane >> 4;     // quad 0..3
    const int lm   = lane & 15;
    const int cw   = wv << 4;       // this wave's h-col base
    const int b0   = blockIdx.x << 4;

    // stride HH+8=72 f16 (144 B): A-frag b128 reads land on distinct bank groups
    __shared__ __align__(16) _Float16 h1buf[2][16][HH + 8];
    __shared__ __align__(16) _Float16 h2buf[2][16][HH + 8];
    __shared__ float ored[4][16];

    // ---- x prefetch (issue first: longest latency) ----
    // A-frag: lane provides A[m=lm][k=q*8+j] per 32-wide kstep s.
    const float* xrow = x + (size_t)(b0 + lm) * TT * DIN + q * 8;
    float4 xa0[8], xa1[8];
    auto prefetch = [&](int t, float4 (&xb)[8]) {
        const float* p = xrow + t * DIN;
        #pragma unroll
        for (int s = 0; s < 4; s++) {
            xb[2 * s]     = *(const float4*)(p + s * 32);
            xb[2 * s + 1] = *(const float4*)(p + s * 32 + 4);
        }
    };
    prefetch(0, xa0);
    prefetch(1, xa1);

    // ---- weight fragments into registers (B-layout: lane = B[k=q*8+j][n=lm]) ----
    // W stored [N=3H][K] row-major, so B-frag = 8 consecutive floats of row n.
    f16x8 wih0[3][4], whh0[3][2], wih1[3][2], whh1[3][2];
    float bi0[3], bh0[3], bi1[3], bh1[3];
    #pragma unroll
    for (int g = 0; g < 3; g++) {
        const int n = g * 64 + cw + lm;
        #pragma unroll
        for (int s = 0; s < 4; s++) {
            const float* p = Wih0 + n * DIN + s * 32 + q * 8;
            #pragma unroll
            for (int j = 0; j < 8; j++) wih0[g][s][j] = (_Float16)p[j];
        }
        #pragma unroll
        for (int s = 0; s < 2; s++) {
            const float* ph = Whh0 + n * HH + s * 32 + q * 8;
            const float* pi = Wih1 + n * HH + s * 32 + q * 8;
            const float* pj = Whh1 + n * HH + s * 32 + q * 8;
            #pragma unroll
            for (int j = 0; j < 8; j++) {
                whh0[g][s][j] = (_Float16)ph[j];
                wih1[g][s][j] = (_Float16)pi[j];
                whh1[g][s][j] = (_Float16)pj[j];
            }
        }
        bi0[g] = bih0[n]; bh0[g] = bhh0[n];
        bi1[g] = bih1[n]; bh1[g] = bhh1[n];
    }

    // ---- zero h state (h0 = 0) ----
    {
        _Float16* z1 = &h1buf[0][0][0];
        _Float16* z2 = &h2buf[0][0][0];
        const int total = 2 * 16 * (HH + 8);
        for (int i = tid; i < total; i += 256) { z1[i] = (_Float16)0; z2[i] = (_Float16)0; }
    }
    float h1C[4] = {0.f, 0.f, 0.f, 0.f};   // C-layout: row q*4+r, col cw+lm
    float h2C[4] = {0.f, 0.f, 0.f, 0.f};
    __syncthreads();

    // ---- one GRU timestep (both layers). ONE barrier per step. ----
    auto step = [&](int t, float4 (&xb)[8]) {
        const int p = t & 1;   // read "old" from buffer p, write "new" to 1-p

        // x A-frags (f32 -> f16)
        f16x8 ax[4];
        #pragma unroll
        for (int s = 0; s < 4; s++) {
            const float4 u = xb[2 * s], v = xb[2 * s + 1];
            ax[s][0] = (_Float16)u.x; ax[s][1] = (_Float16)u.y;
            ax[s][2] = (_Float16)u.z; ax[s][3] = (_Float16)u.w;
            ax[s][4] = (_Float16)v.x; ax[s][5] = (_Float16)v.y;
            ax[s][6] = (_Float16)v.z; ax[s][7] = (_Float16)v.w;
        }
        if (t + 2 < TT) prefetch(t + 2, xb);   // distance-2 prefetch, same buffer

        // ---- layer 0: gx0 = x_t @ Wih0^T + bih0 ; gh0 = h1_old @ Whh0^T + bhh0 ----
        f16x8 ah1[2];
        ah1[0] = *(const f16x8*)&h1buf[p][lm][q * 8];
        ah1[1] = *(const f16x8*)&h1buf[p][lm][32 + q * 8];

        f32x4 agx[3], agh[3];
        #pragma unroll
        for (int g = 0; g < 3; g++) agx[g] = (f32x4){bi0[g], bi0[g], bi0[g], bi0[g]};
        #pragma unroll
        for (int s = 0; s < 4; s++)
            #pragma unroll
            for (int g = 0; g < 3; g++)
                agx[g] = __builtin_amdgcn_mfma_f32_16x16x32_f16(ax[s], wih0[g][s], agx[g], 0, 0, 0);
        #pragma unroll
        for (int g = 0; g < 3; g++) agh[g] = (f32x4){bh0[g], bh0[g], bh0[g], bh0[g]};
        #pragma unroll
        for (int s = 0; s < 2; s++)
            #pragma unroll
            for (int g = 0; g < 3; g++)
                agh[g] = __builtin_amdgcn_mfma_f32_16x16x32_f16(ah1[s], whh0[g][s], agh[g], 0, 0, 0);

        // gates (PyTorch order r,z,n; b_hh_n stays inside r*gh_n)
        #pragma unroll
        for (int r = 0; r < 4; r++) {
            const float rr = fast_sigmoid(agx[0][r] + agh[0][r]);
            const float zz = fast_sigmoid(agx[1][r] + agh[1][r]);
            const float nn = fast_tanh(agx[2][r] + rr * agh[2][r]);
            h1C[r] = nn + zz * (h1C[r] - nn);
            h1buf[1 - p][q * 4 + r][cw + lm] = (_Float16)h1C[r];
        }
        lds_barrier();   // h1_new visible; also licenses all buffer-p overwrites
                         // next iter. vmcnt NOT drained: x prefetch stays in flight.

        // ---- layer 1: gx1 = h1_new @ Wih1^T + bih1 ; gh1 = h2_old @ Whh1^T + bhh1 ----
        f16x8 ah1n[2], ah2[2];
        ah1n[0] = *(const f16x8*)&h1buf[1 - p][lm][q * 8];
        ah1n[1] = *(const f16x8*)&h1buf[1 - p][lm][32 + q * 8];
        ah2[0]  = *(const f16x8*)&h2buf[p][lm][q * 8];
        ah2[1]  = *(const f16x8*)&h2buf[p][lm][32 + q * 8];

        #pragma unroll
        for (int g = 0; g < 3; g++) {
            agx[g] = (f32x4){bi1[g], bi1[g], bi1[g], bi1[g]};
            agh[g] = (f32x4){bh1[g], bh1[g], bh1[g], bh1[g]};
        }
        #pragma unroll
        for (int s = 0; s < 2; s++)
            #pragma unroll
            for (int g = 0; g < 3; g++) {
                agx[g] = __builtin_amdgcn_mfma_f32_16x16x32_f16(ah1n[s], wih1[g][s], agx[g], 0, 0, 0);
                agh[g] = __builtin_amdgcn_mfma_f32_16x16x32_f16(ah2[s],  whh1[g][s], agh[g], 0, 0, 0);
            }
        #pragma unroll
        for (int r = 0; r < 4; r++) {
            const float rr = fast_sigmoid(agx[0][r] + agh[0][r]);
            const float zz = fast_sigmoid(agx[1][r] + agh[1][r]);
            const float nn = fast_tanh(agx[2][r] + rr * agh[2][r]);
            h2C[r] = nn + zz * (h2C[r] - nn);
            h2buf[1 - p][q * 4 + r][cw + lm] = (_Float16)h2C[r];
        }
        // no barrier here: next iter's phase-1/2 reads are covered by next mid-barrier
    };

    for (int t = 0; t < TT; t += 2) {   // unroll x2 so xa0/xa1 indices are compile-time
        step(t, xa0);
        step(t + 1, xa1);
    }

    // ---- out[b] = h2_last[b,:] . Wfc + bfc ----
    const float wf = Wfc[cw + lm];
    float pr[4];
    #pragma unroll
    for (int r = 0; r < 4; r++) pr[r] = h2C[r] * wf;
    #pragma unroll
    for (int m = 1; m < 16; m <<= 1) {
        #pragma unroll
        for (int r = 0; r < 4; r++) pr[r] += __shfl_xor(pr[r], m, 64);
    }
    if (lm == 0) {
        #pragma unroll
        for (int r = 0; r < 4; r++) ored[wv][q * 4 + r] = pr[r];
    }
    __syncthreads();
    if (tid < 16) {
        out[b0 + tid] = ored[0][tid] + ored[1][tid] + ored[2][tid] + ored[3][tid] + bfc[0];
    }
}

extern "C" void kernel_launch(void* const* d_in, const int* in_sizes, int n_in,
                              void* d_out, int out_size, void* d_ws, size_t ws_size,
                              hipStream_t stream) {
    (void)in_sizes; (void)n_in; (void)d_ws; (void)ws_size; (void)out_size;
    const float* x    = (const float*)d_in[0];
    const float* Wih0 = (const float*)d_in[1];
    const float* Whh0 = (const float*)d_in[2];
    const float* bih0 = (const float*)d_in[3];
    const float* bhh0 = (const float*)d_in[4];
    const float* Wih1 = (const float*)d_in[5];
    const float* Whh1 = (const float*)d_in[6];
    const float* bih1 = (const float*)d_in[7];
    const float* bhh1 = (const float*)d_in[8];
    const float* Wfc  = (const float*)d_in[9];
    const float* bfc  = (const float*)d_in[10];
    float* out = (float*)d_out;

    gru_fused_kernel<<<dim3(4096 / 16), dim3(256), 0, stream>>>(
        x, Wih0, Whh0, bih0, bhh0, Wih1, Whh1, bih1, bhh1, Wfc, bfc, out);
}